// Round 3
// 302.124 us; speedup vs baseline: 1.0553x; 1.0553x over previous
//
#include <hip/hip_runtime.h>

// StyleWSConv as 9-position implicit GEMM, bf16 MFMA (16x16x32), fp32 accum.
// out[b,co,p] = g[b,co] * sum_{pos,ci} wt[co,pos,ci] * xt[b,ci,p+shift(pos)]
//               + bias[co] + noise[b,p]*ns
// wt = w/wmax[co] (bf16), xt = t[b,ci]*x (bf16, padded NHWC), g fp32.
//
// This revision (T2-only isolation on the proven baseline structure):
//  - XOR-swizzled LDS (16B chunk ^= (row>>1)&3) for sA and sB:
//    inverse-swizzled global source (global_load_lds dest stays linear) +
//    swizzled read addresses -> 8-way bank conflict -> 2-way (free, m136).
//  - border-only zeroing of xbp (2.1 MB instead of 35.7 MB).
//  - barrier structure UNCHANGED from the 318us baseline (__syncthreads()).

#define EPSV   1e-8f
#define SCALEV 0.014731391274719738f  // 1/sqrt(512*9)

typedef __attribute__((ext_vector_type(8))) short short8;
typedef __attribute__((ext_vector_type(4))) float floatx4;

__device__ __forceinline__ void gload_lds16(const void* g, void* l) {
    __builtin_amdgcn_global_load_lds(
        (const __attribute__((address_space(1))) void*)g,
        (__attribute__((address_space(3))) void*)l, 16, 0, 0);
}

__device__ __forceinline__ unsigned short f2bf(float f) {
    unsigned u = __float_as_uint(f);
    unsigned r = (u + 0x7fffu + ((u >> 16) & 1u)) >> 16;
    return (unsigned short)r;
}

// ---------------- zero only the halo of xbp ----------------
// xbp = [8][66][66][512] bf16. Interior (h 1..64, w 1..64) is fully written
// by prep_x; only rows 0,65 and cols 0,65 need zeros.
// Per b: 260 cells (66 + 66 + 64*2) x 512 elems = 64 uint4 per cell.
__global__ __launch_bounds__(256) void zero_border(uint4* __restrict__ xbp4) {
    int idx = blockIdx.x * 256 + threadIdx.x;   // 8 * 260 * 64 = 133120
    if (idx >= 133120) return;
    int q    = idx & 63;
    int cell = (idx >> 6) % 260;
    int b    = idx / 16640;
    int h, w;
    if (cell < 66)       { h = 0;  w = cell; }
    else if (cell < 132) { h = 65; w = cell - 66; }
    else { int e = cell - 132; h = 1 + (e >> 1); w = (e & 1) * 65; }
    uint4 z = {0u, 0u, 0u, 0u};
    xbp4[(size_t)((b * 66 + h) * 66 + w) * 64 + q] = z;
}

// ---------------- style inf-norm: t[b][ci] ----------------
__global__ __launch_bounds__(512) void prep_style(
    const float* __restrict__ style, float* __restrict__ tbuf)
{
    const int b = blockIdx.x, t = threadIdx.x;
    float v = style[b * 512 + t];
    __shared__ float red[512];
    red[t] = fabsf(v);
    __syncthreads();
    for (int s = 256; s > 0; s >>= 1) {
        if (t < s) red[t] = fmaxf(red[t], red[t + s]);
        __syncthreads();
    }
    tbuf[b * 512 + t] = v / red[0];
}

// ---------------- weights: wmax-normalize -> bf16 Aw[co][9][512]; wsqn ----------------
__global__ __launch_bounds__(256) void prep_w(
    const float* __restrict__ weight, float* __restrict__ wsqn,
    unsigned short* __restrict__ Aw)
{
    const int co = blockIdx.x, t = threadIdx.x;
    const float* wp = weight + (size_t)co * 4608;
    float m = 0.f;
    for (int i = t; i < 4608; i += 256) m = fmaxf(m, fabsf(wp[i]));
    __shared__ float red[256];
    red[t] = m;
    __syncthreads();
    for (int s = 128; s > 0; s >>= 1) {
        if (t < s) red[t] = fmaxf(red[t], red[t + s]);
        __syncthreads();
    }
    const float inv = 1.f / red[0];
    for (int ci = t; ci < 512; ci += 256) {
        float s = 0.f;
        #pragma unroll
        for (int k = 0; k < 9; ++k) {
            float v = wp[ci * 9 + k] * inv;
            s = fmaf(v, v, s);
            Aw[(size_t)(co * 9 + k) * 512 + ci] = f2bf(v);
        }
        wsqn[co * 512 + ci] = s;
    }
}

// ---------------- x -> padded NHWC bf16 with t folded: xbp[b][66][66][512] ----------------
__global__ __launch_bounds__(256) void prep_x(
    const float* __restrict__ x, const float* __restrict__ tbuf,
    unsigned short* __restrict__ xbp)
{
    const int cic = blockIdx.x;  // 16 chunks of 32 ci
    const int h   = blockIdx.y;  // 64
    const int b   = blockIdx.z;  // 8
    const int tid = threadIdx.x;
    __shared__ float tr[64][33];

    const int cl = tid >> 3;           // 0..31 ci-local
    const int w0 = (tid & 7) << 3;     // 0..56
    const int ci = cic * 32 + cl;
    const float tv = tbuf[b * 512 + ci];
    const float* xp = x + (((size_t)(b * 512 + ci)) << 12) + (h << 6) + w0;
    float4 u = *(const float4*)xp;
    float4 v = *(const float4*)(xp + 4);
    tr[w0 + 0][cl] = u.x * tv; tr[w0 + 1][cl] = u.y * tv;
    tr[w0 + 2][cl] = u.z * tv; tr[w0 + 3][cl] = u.w * tv;
    tr[w0 + 4][cl] = v.x * tv; tr[w0 + 5][cl] = v.y * tv;
    tr[w0 + 6][cl] = v.z * tv; tr[w0 + 7][cl] = v.w * tv;
    __syncthreads();

    const int w  = tid >> 2;           // 0..63
    const int c8 = (tid & 3) << 3;     // 0,8,16,24
    unsigned short o[8] __attribute__((aligned(16)));
    #pragma unroll
    for (int j = 0; j < 8; ++j) o[j] = f2bf(tr[w][c8 + j]);
    size_t dst = ((size_t)((b * 66 + h + 1) * 66) + (w + 1)) * 512 + cic * 32 + c8;
    *(uint4*)&xbp[dst] = *(const uint4*)o;
}

// ---------------- demod coefficient g[b][co] ----------------
__global__ __launch_bounds__(256) void gcoef(
    const float* __restrict__ wsqn, const float* __restrict__ tbuf,
    float* __restrict__ gbuf)
{
    const int b    = blockIdx.y;
    const int co   = blockIdx.x * 4 + (threadIdx.x >> 6);
    const int lane = threadIdx.x & 63;
    float sum = 0.f;
    for (int ci = lane; ci < 512; ci += 64) {
        float tv = tbuf[b * 512 + ci];
        sum = fmaf(tv * tv, wsqn[co * 512 + ci], sum);
    }
    #pragma unroll
    for (int off = 32; off > 0; off >>= 1) sum += __shfl_down(sum, off);
    if (lane == 0)
        gbuf[b * 512 + co] = SCALEV * SCALEV / sqrtf(fmaf(SCALEV * SCALEV, sum, EPSV));
}

// ---------------- main: implicit-GEMM conv, 128co x 128px tile ----------------
// grid (32 px-blocks [16h x 2w], 4 co-blocks, 8 b), 256 threads (4 waves 2x2).
// K-chunk = 64 ci (two 32-ci LDS half-buffers), 9 kernel positions reuse B-tile.
// LDS rows (64B = 4x16B chunks) XOR-swizzled: LDS(row,c) = data(row, c^((row>>1)&3)),
// written via inverse-swizzled global source (global_load_lds dest linear),
// read with the same XOR -> 2 lanes/bank (free per m136).
__global__ __launch_bounds__(256, 2) void conv_mfma(
    const unsigned short* __restrict__ xbp, const unsigned short* __restrict__ Aw,
    const float* __restrict__ gbuf, const float* __restrict__ bias,
    const float* __restrict__ noise, const float* __restrict__ nstr,
    float* __restrict__ out)
{
    __shared__ __align__(16) short sA[2][4096];   // 128co x 32ci per half
    __shared__ __align__(16) short sB[2][6656];   // 208px(6r x 34c, padded) x 32ci per half

    const int tid  = threadIdx.x;
    const int lane = tid & 63;
    const int wv   = tid >> 6;
    const int b    = blockIdx.z;
    const int co0  = blockIdx.y << 7;
    const int h0   = (blockIdx.x >> 1) << 2;   // output row start (== padded row start)
    const int w0   = (blockIdx.x & 1) << 5;

    const int n0  = lane & 15;
    const int kq  = lane >> 4;
    const int wco = (wv >> 1) << 6;
    const int wpx = (wv & 1) << 6;

    int pb[4], aoff[4];
    #pragma unroll
    for (int fj = 0; fj < 4; ++fj) {
        int p = wpx + fj * 16 + n0;
        pb[fj] = (p >> 5) * 34 + (p & 31);     // base px index in 6x34 layout
    }
    #pragma unroll
    for (int fi = 0; fi < 4; ++fi) {
        int row = wco + fi * 16 + n0;
        aoff[fi] = row * 32 + (((kq ^ (n0 >> 1)) & 3) << 3);  // swizzled read
    }

    // staging: lane -> row sl_px, source 16B chunk inverse-swizzled so the
    // linear LDS write (dest + lane*16B) lands the swizzled layout.
    const int sl_px = lane >> 2;
    const int sw_ci = (((lane & 3) ^ (sl_px >> 1)) & 3) << 3;

    floatx4 zz = {0.f, 0.f, 0.f, 0.f};
    floatx4 acc[4][4];
    #pragma unroll
    for (int i = 0; i < 4; ++i)
        #pragma unroll
        for (int j = 0; j < 4; ++j) acc[i][j] = zz;

    const unsigned short* xb = xbp + (size_t)b * 4356 * 512;

    for (int ci0 = 0; ci0 < 512; ci0 += 64) {
        __syncthreads();
        // stage B tile: 6 rows x 34 cols x 64 ci (two halves), 13 wave-instrs/half
        #pragma unroll
        for (int hf = 0; hf < 2; ++hf) {
            const unsigned short* src = xb + ci0 + hf * 32 + sw_ci;
            for (int j = wv; j < 13; j += 4) {
                int px = j * 16 + sl_px;
                if (px > 203) px = 203;
                int row = px / 34;
                int col = px - row * 34;
                gload_lds16(src + (((size_t)(h0 + row) * 66 + w0 + col) << 9),
                            &sB[hf][j * 512]);
            }
        }
        #pragma unroll 1
        for (int pos = 0; pos < 9; ++pos) {
            const int kh = pos / 3;
            const int kw = pos - kh * 3;
            if (pos) __syncthreads();
            // stage A tile for this position: 128co x 64ci
            #pragma unroll
            for (int hf = 0; hf < 2; ++hf) {
                for (int j = wv; j < 8; j += 4) {
                    int co = j * 16 + sl_px;
                    gload_lds16(Aw + (size_t)((co0 + co) * 9 + pos) * 512
                                   + ci0 + hf * 32 + sw_ci,
                                &sA[hf][j * 512]);
                }
            }
            __syncthreads();
            const int dpos = kh * 34 + kw;
            #pragma unroll
            for (int hf = 0; hf < 2; ++hf) {
                short8 af[4], bfr[4];
                #pragma unroll
                for (int fi = 0; fi < 4; ++fi)
                    af[fi] = *(const short8*)&sA[hf][aoff[fi]];
                #pragma unroll
                for (int fj = 0; fj < 4; ++fj) {
                    int pr = pb[fj] + dpos;
                    bfr[fj] = *(const short8*)
                        &sB[hf][pr * 32 + (((kq ^ (pr >> 1)) & 3) << 3)];
                }
                #pragma unroll
                for (int fi = 0; fi < 4; ++fi)
                    #pragma unroll
                    for (int fj = 0; fj < 4; ++fj)
                        acc[fi][fj] = __builtin_amdgcn_mfma_f32_16x16x32_bf16(
                            af[fi], bfr[fj], acc[fi][fj], 0, 0, 0);
            }
        }
    }

    // epilogue: out = g*acc + bias + noise*ns
    const float ns = nstr[0];
    float nz[4];
    int ph[4], pw[4];
    #pragma unroll
    for (int fj = 0; fj < 4; ++fj) {
        int p = wpx + fj * 16 + n0;
        ph[fj] = h0 + (p >> 5);
        pw[fj] = w0 + (p & 31);
        nz[fj] = noise[(b << 12) + (ph[fj] << 6) + pw[fj]] * ns;
    }
    #pragma unroll
    for (int fi = 0; fi < 4; ++fi) {
        #pragma unroll
        for (int i = 0; i < 4; ++i) {
            int co = co0 + wco + fi * 16 + kq * 4 + i;
            float gg = gbuf[(b << 9) + co];
            float bb = bias[co];
            #pragma unroll
            for (int fj = 0; fj < 4; ++fj) {
                out[(((size_t)((b << 9) + co)) << 12) + (ph[fj] << 6) + pw[fj]] =
                    fmaf(gg, acc[fi][fj][i], bb + nz[fj]);
            }
        }
    }
}

extern "C" void kernel_launch(void* const* d_in, const int* in_sizes, int n_in,
                              void* d_out, int out_size, void* d_ws, size_t ws_size,
                              hipStream_t stream)
{
    const float* x      = (const float*)d_in[0];
    const float* style  = (const float*)d_in[1];
    const float* noise  = (const float*)d_in[2];
    const float* weight = (const float*)d_in[3];
    const float* bias   = (const float*)d_in[4];
    const float* nstr   = (const float*)d_in[5];
    float* out = (float*)d_out;
    char* ws = (char*)d_ws;

    // workspace layout (bytes)
    float*          tbuf = (float*)(ws);                    // 16384
    float*          gbuf = (float*)(ws + 16384);            // 16384
    float*          wsqn = (float*)(ws + 32768);            // 1048576
    unsigned short* Aw   = (unsigned short*)(ws + 1081344); // 4718592
    unsigned short* xbp  = (unsigned short*)(ws + 5799936); // 35684352 -> total ~41.5 MB

    hipLaunchKernelGGL(zero_border, dim3(520), dim3(256), 0, stream, (uint4*)xbp);
    hipLaunchKernelGGL(prep_style, dim3(8), dim3(512), 0, stream, style, tbuf);
    hipLaunchKernelGGL(prep_w, dim3(512), dim3(256), 0, stream, weight, wsqn, Aw);
    hipLaunchKernelGGL(prep_x, dim3(16, 64, 8), dim3(256), 0, stream, x, tbuf, xbp);
    hipLaunchKernelGGL(gcoef, dim3(128, 8), dim3(256), 0, stream, wsqn, tbuf, gbuf);
    hipLaunchKernelGGL(conv_mfma, dim3(32, 4, 8), dim3(256), 0, stream,
                       xbp, Aw, gbuf, bias, noise, nstr, out);
}

// Round 4
// 298.503 us; speedup vs baseline: 1.0681x; 1.0121x over previous
//
#include <hip/hip_runtime.h>

// StyleWSConv as 9-position implicit GEMM, bf16 MFMA (16x16x32), fp32 accum.
// out[b,co,p] = g[b,co] * sum_{pos,ci} wt[co,pos,ci] * xt[b,ci,p+shift(pos)]
//               + bias[co] + noise[b,p]*ns
// wt = w/wmax[co] (bf16), xt = t[b,ci]*x (bf16, padded NHWC), g fp32.
//
// This revision (on top of round-2's verified T2 swizzle, conflicts == 0):
//  - sA 2-slot ring double-buffer across the 9 positions: stage pos+1 before
//    the barrier, counted s_waitcnt vmcnt(4) (loads stay in flight across the
//    barrier), full vmcnt(0) drain only at the chunk boundary (8x not 72x).
//  - s_setprio(1) around the MFMA cluster (phase-split now exists -> T5 pays).
//  - grid reordered (co fastest): round-robin XCD assignment pins each XCD to
//    one co-group -> per-XCD Aw working set 4.7 MB -> 1.18 MB (fits 4 MB L2).

#define EPSV   1e-8f
#define SCALEV 0.014731391274719738f  // 1/sqrt(512*9)

typedef __attribute__((ext_vector_type(8))) short short8;
typedef __attribute__((ext_vector_type(4))) float floatx4;

__device__ __forceinline__ void gload_lds16(const void* g, void* l) {
    __builtin_amdgcn_global_load_lds(
        (const __attribute__((address_space(1))) void*)g,
        (__attribute__((address_space(3))) void*)l, 16, 0, 0);
}

__device__ __forceinline__ unsigned short f2bf(float f) {
    unsigned u = __float_as_uint(f);
    unsigned r = (u + 0x7fffu + ((u >> 16) & 1u)) >> 16;
    return (unsigned short)r;
}

// ---------------- zero only the halo of xbp ----------------
// xbp = [8][66][66][512] bf16. Interior (h 1..64, w 1..64) is fully written
// by prep_x; only rows 0,65 and cols 0,65 need zeros.
// Per b: 260 cells (66 + 66 + 64*2) x 512 elems = 64 uint4 per cell.
__global__ __launch_bounds__(256) void zero_border(uint4* __restrict__ xbp4) {
    int idx = blockIdx.x * 256 + threadIdx.x;   // 8 * 260 * 64 = 133120
    if (idx >= 133120) return;
    int q    = idx & 63;
    int cell = (idx >> 6) % 260;
    int b    = idx / 16640;
    int h, w;
    if (cell < 66)       { h = 0;  w = cell; }
    else if (cell < 132) { h = 65; w = cell - 66; }
    else { int e = cell - 132; h = 1 + (e >> 1); w = (e & 1) * 65; }
    uint4 z = {0u, 0u, 0u, 0u};
    xbp4[(size_t)((b * 66 + h) * 66 + w) * 64 + q] = z;
}

// ---------------- style inf-norm: t[b][ci] ----------------
__global__ __launch_bounds__(512) void prep_style(
    const float* __restrict__ style, float* __restrict__ tbuf)
{
    const int b = blockIdx.x, t = threadIdx.x;
    float v = style[b * 512 + t];
    __shared__ float red[512];
    red[t] = fabsf(v);
    __syncthreads();
    for (int s = 256; s > 0; s >>= 1) {
        if (t < s) red[t] = fmaxf(red[t], red[t + s]);
        __syncthreads();
    }
    tbuf[b * 512 + t] = v / red[0];
}

// ---------------- weights: wmax-normalize -> bf16 Aw[co][9][512]; wsqn ----------------
__global__ __launch_bounds__(256) void prep_w(
    const float* __restrict__ weight, float* __restrict__ wsqn,
    unsigned short* __restrict__ Aw)
{
    const int co = blockIdx.x, t = threadIdx.x;
    const float* wp = weight + (size_t)co * 4608;
    float m = 0.f;
    for (int i = t; i < 4608; i += 256) m = fmaxf(m, fabsf(wp[i]));
    __shared__ float red[256];
    red[t] = m;
    __syncthreads();
    for (int s = 128; s > 0; s >>= 1) {
        if (t < s) red[t] = fmaxf(red[t], red[t + s]);
        __syncthreads();
    }
    const float inv = 1.f / red[0];
    for (int ci = t; ci < 512; ci += 256) {
        float s = 0.f;
        #pragma unroll
        for (int k = 0; k < 9; ++k) {
            float v = wp[ci * 9 + k] * inv;
            s = fmaf(v, v, s);
            Aw[(size_t)(co * 9 + k) * 512 + ci] = f2bf(v);
        }
        wsqn[co * 512 + ci] = s;
    }
}

// ---------------- x -> padded NHWC bf16 with t folded: xbp[b][66][66][512] ----------------
__global__ __launch_bounds__(256) void prep_x(
    const float* __restrict__ x, const float* __restrict__ tbuf,
    unsigned short* __restrict__ xbp)
{
    const int cic = blockIdx.x;  // 16 chunks of 32 ci
    const int h   = blockIdx.y;  // 64
    const int b   = blockIdx.z;  // 8
    const int tid = threadIdx.x;
    __shared__ float tr[64][33];

    const int cl = tid >> 3;           // 0..31 ci-local
    const int w0 = (tid & 7) << 3;     // 0..56
    const int ci = cic * 32 + cl;
    const float tv = tbuf[b * 512 + ci];
    const float* xp = x + (((size_t)(b * 512 + ci)) << 12) + (h << 6) + w0;
    float4 u = *(const float4*)xp;
    float4 v = *(const float4*)(xp + 4);
    tr[w0 + 0][cl] = u.x * tv; tr[w0 + 1][cl] = u.y * tv;
    tr[w0 + 2][cl] = u.z * tv; tr[w0 + 3][cl] = u.w * tv;
    tr[w0 + 4][cl] = v.x * tv; tr[w0 + 5][cl] = v.y * tv;
    tr[w0 + 6][cl] = v.z * tv; tr[w0 + 7][cl] = v.w * tv;
    __syncthreads();

    const int w  = tid >> 2;           // 0..63
    const int c8 = (tid & 3) << 3;     // 0,8,16,24
    unsigned short o[8] __attribute__((aligned(16)));
    #pragma unroll
    for (int j = 0; j < 8; ++j) o[j] = f2bf(tr[w][c8 + j]);
    size_t dst = ((size_t)((b * 66 + h + 1) * 66) + (w + 1)) * 512 + cic * 32 + c8;
    *(uint4*)&xbp[dst] = *(const uint4*)o;
}

// ---------------- demod coefficient g[b][co] ----------------
__global__ __launch_bounds__(256) void gcoef(
    const float* __restrict__ wsqn, const float* __restrict__ tbuf,
    float* __restrict__ gbuf)
{
    const int b    = blockIdx.y;
    const int co   = blockIdx.x * 4 + (threadIdx.x >> 6);
    const int lane = threadIdx.x & 63;
    float sum = 0.f;
    for (int ci = lane; ci < 512; ci += 64) {
        float tv = tbuf[b * 512 + ci];
        sum = fmaf(tv * tv, wsqn[co * 512 + ci], sum);
    }
    #pragma unroll
    for (int off = 32; off > 0; off >>= 1) sum += __shfl_down(sum, off);
    if (lane == 0)
        gbuf[b * 512 + co] = SCALEV * SCALEV / sqrtf(fmaf(SCALEV * SCALEV, sum, EPSV));
}

// ---------------- main: implicit-GEMM conv, 128co x 128px tile ----------------
// grid (4 co-blocks, 32 px-blocks [16h x 2w], 8 b), 256 threads (4 waves 2x2).
// co fastest-varying -> round-robin XCD dispatch pins each XCD to one co-group
// (per-XCD Aw working set 1.18 MB, fits the 4 MB L2).
// K-chunk = 64 ci. sB staged once per chunk; sA ring double-buffered across
// the 9 positions with counted vmcnt(4) + raw barriers (full drain only at
// chunk boundary). LDS rows (64B = 4x16B chunks) XOR-swizzled:
//   LDS(row, c) = data(row, c ^ ((row>>1)&3))
// written via inverse-swizzled global source (global_load_lds dest linear),
// read with the same XOR -> conflict-free (verified: SQ_LDS_BANK_CONFLICT==0).
__global__ __launch_bounds__(256, 2) void conv_mfma(
    const unsigned short* __restrict__ xbp, const unsigned short* __restrict__ Aw,
    const float* __restrict__ gbuf, const float* __restrict__ bias,
    const float* __restrict__ noise, const float* __restrict__ nstr,
    float* __restrict__ out)
{
    __shared__ __align__(16) short sA[2][8192];   // ring x (2hf x 128co x 32ci)
    __shared__ __align__(16) short sB[2][6656];   // hf x 208px(6r x 34c) x 32ci

    const int tid  = threadIdx.x;
    const int lane = tid & 63;
    const int wv   = tid >> 6;
    const int b    = blockIdx.z;
    const int co0  = blockIdx.x << 7;
    const int h0   = (blockIdx.y >> 1) << 2;   // output row start (== padded row start)
    const int w0   = (blockIdx.y & 1) << 5;

    const int n0  = lane & 15;
    const int kq  = lane >> 4;
    const int wco = (wv >> 1) << 6;
    const int wpx = (wv & 1) << 6;

    int pb[4], aoff[4];
    #pragma unroll
    for (int fj = 0; fj < 4; ++fj) {
        int p = wpx + fj * 16 + n0;
        pb[fj] = (p >> 5) * 34 + (p & 31);     // base px index in 6x34 layout
    }
    #pragma unroll
    for (int fi = 0; fi < 4; ++fi) {
        int row = wco + fi * 16 + n0;
        aoff[fi] = row * 32 + (((kq ^ (n0 >> 1)) & 3) << 3);  // swizzled read
    }

    // staging: lane -> row sl_px, source 16B chunk inverse-swizzled so the
    // linear LDS write (dest + lane*16B) lands the swizzled layout.
    const int sl_px = lane >> 2;
    const int sw_ci = (((lane & 3) ^ (sl_px >> 1)) & 3) << 3;

    floatx4 zz = {0.f, 0.f, 0.f, 0.f};
    floatx4 acc[4][4];
    #pragma unroll
    for (int i = 0; i < 4; ++i)
        #pragma unroll
        for (int j = 0; j < 4; ++j) acc[i][j] = zz;

    const unsigned short* xb = xbp + (size_t)b * 4356 * 512;

    auto stageB = [&](int ci0) {
        #pragma unroll
        for (int hf = 0; hf < 2; ++hf) {
            const unsigned short* src = xb + ci0 + hf * 32 + sw_ci;
            for (int j = wv; j < 13; j += 4) {
                int px = j * 16 + sl_px;
                if (px > 203) px = 203;
                int row = px / 34;
                int col = px - row * 34;
                gload_lds16(src + (((size_t)(h0 + row) * 66 + w0 + col) << 9),
                            &sB[hf][j * 512]);
            }
        }
    };
    auto stageA = [&](int ci0, int pos, int rs) {
        #pragma unroll
        for (int hf = 0; hf < 2; ++hf) {
            #pragma unroll
            for (int j = wv; j < 8; j += 4) {   // 2 iters per wave
                int co = j * 16 + sl_px;
                gload_lds16(Aw + (size_t)((co0 + co) * 9 + pos) * 512
                               + ci0 + hf * 32 + sw_ci,
                            &sA[rs][hf * 4096 + j * 512]);
            }
        }
    };

    // prologue: B(chunk0) + A(chunk0,pos0) -> ring slot 0, full drain once.
    stageB(0);
    stageA(0, 0, 0);
    asm volatile("s_waitcnt vmcnt(0)" ::: "memory");
    __builtin_amdgcn_s_barrier();

    int ring = 0;
    #pragma unroll 1
    for (int ci0 = 0; ci0 < 512; ci0 += 64) {
        #pragma unroll 1
        for (int pos = 0; pos < 9; ++pos) {
            if (pos < 8) {
                // issue next position's A into the other ring slot; its 4
                // loads stay in flight across the barrier (counted wait).
                stageA(ci0, pos + 1, ring ^ 1);
                asm volatile("s_waitcnt vmcnt(4)" ::: "memory");
            } else {
                // chunk boundary next: sB single-buffered -> full drain.
                asm volatile("s_waitcnt vmcnt(0)" ::: "memory");
            }
            __builtin_amdgcn_s_barrier();   // this phase's stages have landed

            const int kh   = pos / 3;
            const int dpos = kh * 34 + (pos - kh * 3);

            __builtin_amdgcn_s_setprio(1);
            #pragma unroll
            for (int hf = 0; hf < 2; ++hf) {
                short8 af[4], bfr[4];
                #pragma unroll
                for (int fi = 0; fi < 4; ++fi)
                    af[fi] = *(const short8*)&sA[ring][hf * 4096 + aoff[fi]];
                #pragma unroll
                for (int fj = 0; fj < 4; ++fj) {
                    int pr = pb[fj] + dpos;
                    bfr[fj] = *(const short8*)
                        &sB[hf][pr * 32 + (((kq ^ (pr >> 1)) & 3) << 3)];
                }
                #pragma unroll
                for (int fi = 0; fi < 4; ++fi)
                    #pragma unroll
                    for (int fj = 0; fj < 4; ++fj)
                        acc[fi][fj] = __builtin_amdgcn_mfma_f32_16x16x32_bf16(
                            af[fi], bfr[fj], acc[fi][fj], 0, 0, 0);
            }
            __builtin_amdgcn_s_setprio(0);
            __builtin_amdgcn_s_barrier();   // protect slot overwritten next phase
            ring ^= 1;
        }
        if (ci0 < 448) {
            // past pos8's 2nd barrier: safe to overwrite sB and sA[ring]
            stageB(ci0 + 64);
            stageA(ci0 + 64, 0, ring);
        }
    }

    // epilogue: out = g*acc + bias + noise*ns
    const float ns = nstr[0];
    float nz[4];
    int ph[4], pw[4];
    #pragma unroll
    for (int fj = 0; fj < 4; ++fj) {
        int p = wpx + fj * 16 + n0;
        ph[fj] = h0 + (p >> 5);
        pw[fj] = w0 + (p & 31);
        nz[fj] = noise[(b << 12) + (ph[fj] << 6) + pw[fj]] * ns;
    }
    #pragma unroll
    for (int fi = 0; fi < 4; ++fi) {
        #pragma unroll
        for (int i = 0; i < 4; ++i) {
            int co = co0 + wco + fi * 16 + kq * 4 + i;
            float gg = gbuf[(b << 9) + co];
            float bb = bias[co];
            #pragma unroll
            for (int fj = 0; fj < 4; ++fj) {
                out[(((size_t)((b << 9) + co)) << 12) + (ph[fj] << 6) + pw[fj]] =
                    fmaf(gg, acc[fi][fj][i], bb + nz[fj]);
            }
        }
    }
}

extern "C" void kernel_launch(void* const* d_in, const int* in_sizes, int n_in,
                              void* d_out, int out_size, void* d_ws, size_t ws_size,
                              hipStream_t stream)
{
    const float* x      = (const float*)d_in[0];
    const float* style  = (const float*)d_in[1];
    const float* noise  = (const float*)d_in[2];
    const float* weight = (const float*)d_in[3];
    const float* bias   = (const float*)d_in[4];
    const float* nstr   = (const float*)d_in[5];
    float* out = (float*)d_out;
    char* ws = (char*)d_ws;

    // workspace layout (bytes)
    float*          tbuf = (float*)(ws);                    // 16384
    float*          gbuf = (float*)(ws + 16384);            // 16384
    float*          wsqn = (float*)(ws + 32768);            // 1048576
    unsigned short* Aw   = (unsigned short*)(ws + 1081344); // 4718592
    unsigned short* xbp  = (unsigned short*)(ws + 5799936); // 35684352 -> total ~41.5 MB

    hipLaunchKernelGGL(zero_border, dim3(520), dim3(256), 0, stream, (uint4*)xbp);
    hipLaunchKernelGGL(prep_style, dim3(8), dim3(512), 0, stream, style, tbuf);
    hipLaunchKernelGGL(prep_w, dim3(512), dim3(256), 0, stream, weight, wsqn, Aw);
    hipLaunchKernelGGL(prep_x, dim3(16, 64, 8), dim3(256), 0, stream, x, tbuf, xbp);
    hipLaunchKernelGGL(gcoef, dim3(128, 8), dim3(256), 0, stream, wsqn, tbuf, gbuf);
    hipLaunchKernelGGL(conv_mfma, dim3(4, 32, 8), dim3(256), 0, stream,
                       xbp, Aw, gbuf, bias, noise, nstr, out);
}

// Round 6
// 272.312 us; speedup vs baseline: 1.1708x; 1.0962x over previous
//
#include <hip/hip_runtime.h>

// StyleWSConv as 9-position implicit GEMM, bf16 MFMA (16x16x32), fp32 accum.
// out[b,co,p] = g[b,co] * sum_{pos,ci} wt[co,pos,ci] * xt[b,ci,p+shift(pos)]
//               + bias[co] + noise[b,p]*ns
// wt = w/wmax[co] (bf16), xt = t[b,ci]*x (bf16, padded NHWC), g fp32.
//
// This revision (single variable vs round 3; identical resubmit of round 5 —
// round-5 bench died to an infra flake, same as rounds 1/2 where identical
// text later passed):
//  - per-wave tile 128co x 64px (8x4 fragments, m201 wave shape); block
//    256co x 128px, grid (32px, 2co, 8b) = 512 blocks = 2/CU. 64 MFMA per
//    barrier pair per wave (2x amortization), LDS 58 KB keeps 2 blocks/CU.
//  - sync structure = proven round-3 (plain __syncthreads, single sA buffer;
//    round 4 showed ring/vmcnt/setprio all neutral on this structure class).
//  - grid px-fastest (round-4 co-fastest raised FETCH 15 MB for 0 perf).
//  - XOR-swizzled LDS retained (verified SQ_LDS_BANK_CONFLICT == 0).

#define EPSV   1e-8f
#define SCALEV 0.014731391274719738f  // 1/sqrt(512*9)

typedef __attribute__((ext_vector_type(8))) short short8;
typedef __attribute__((ext_vector_type(4))) float floatx4;

__device__ __forceinline__ void gload_lds16(const void* g, void* l) {
    __builtin_amdgcn_global_load_lds(
        (const __attribute__((address_space(1))) void*)g,
        (__attribute__((address_space(3))) void*)l, 16, 0, 0);
}

__device__ __forceinline__ unsigned short f2bf(float f) {
    unsigned u = __float_as_uint(f);
    unsigned r = (u + 0x7fffu + ((u >> 16) & 1u)) >> 16;
    return (unsigned short)r;
}

// ---------------- zero only the halo of xbp ----------------
// xbp = [8][66][66][512] bf16. Interior (h 1..64, w 1..64) is fully written
// by prep_x; only rows 0,65 and cols 0,65 need zeros.
// Per b: 260 cells (66 + 66 + 64*2) x 512 elems = 64 uint4 per cell.
__global__ __launch_bounds__(256) void zero_border(uint4* __restrict__ xbp4) {
    int idx = blockIdx.x * 256 + threadIdx.x;   // 8 * 260 * 64 = 133120
    if (idx >= 133120) return;
    int q    = idx & 63;
    int cell = (idx >> 6) % 260;
    int b    = idx / 16640;
    int h, w;
    if (cell < 66)       { h = 0;  w = cell; }
    else if (cell < 132) { h = 65; w = cell - 66; }
    else { int e = cell - 132; h = 1 + (e >> 1); w = (e & 1) * 65; }
    uint4 z = {0u, 0u, 0u, 0u};
    xbp4[(size_t)((b * 66 + h) * 66 + w) * 64 + q] = z;
}

// ---------------- style inf-norm: t[b][ci] ----------------
__global__ __launch_bounds__(512) void prep_style(
    const float* __restrict__ style, float* __restrict__ tbuf)
{
    const int b = blockIdx.x, t = threadIdx.x;
    float v = style[b * 512 + t];
    __shared__ float red[512];
    red[t] = fabsf(v);
    __syncthreads();
    for (int s = 256; s > 0; s >>= 1) {
        if (t < s) red[t] = fmaxf(red[t], red[t + s]);
        __syncthreads();
    }
    tbuf[b * 512 + t] = v / red[0];
}

// ---------------- weights: wmax-normalize -> bf16 Aw[co][9][512]; wsqn ----------------
__global__ __launch_bounds__(256) void prep_w(
    const float* __restrict__ weight, float* __restrict__ wsqn,
    unsigned short* __restrict__ Aw)
{
    const int co = blockIdx.x, t = threadIdx.x;
    const float* wp = weight + (size_t)co * 4608;
    float m = 0.f;
    for (int i = t; i < 4608; i += 256) m = fmaxf(m, fabsf(wp[i]));
    __shared__ float red[256];
    red[t] = m;
    __syncthreads();
    for (int s = 128; s > 0; s >>= 1) {
        if (t < s) red[t] = fmaxf(red[t], red[t + s]);
        __syncthreads();
    }
    const float inv = 1.f / red[0];
    for (int ci = t; ci < 512; ci += 256) {
        float s = 0.f;
        #pragma unroll
        for (int k = 0; k < 9; ++k) {
            float v = wp[ci * 9 + k] * inv;
            s = fmaf(v, v, s);
            Aw[(size_t)(co * 9 + k) * 512 + ci] = f2bf(v);
        }
        wsqn[co * 512 + ci] = s;
    }
}

// ---------------- x -> padded NHWC bf16 with t folded: xbp[b][66][66][512] ----------------
__global__ __launch_bounds__(256) void prep_x(
    const float* __restrict__ x, const float* __restrict__ tbuf,
    unsigned short* __restrict__ xbp)
{
    const int cic = blockIdx.x;  // 16 chunks of 32 ci
    const int h   = blockIdx.y;  // 64
    const int b   = blockIdx.z;  // 8
    const int tid = threadIdx.x;
    __shared__ float tr[64][33];

    const int cl = tid >> 3;           // 0..31 ci-local
    const int w0 = (tid & 7) << 3;     // 0..56
    const int ci = cic * 32 + cl;
    const float tv = tbuf[b * 512 + ci];
    const float* xp = x + (((size_t)(b * 512 + ci)) << 12) + (h << 6) + w0;
    float4 u = *(const float4*)xp;
    float4 v = *(const float4*)(xp + 4);
    tr[w0 + 0][cl] = u.x * tv; tr[w0 + 1][cl] = u.y * tv;
    tr[w0 + 2][cl] = u.z * tv; tr[w0 + 3][cl] = u.w * tv;
    tr[w0 + 4][cl] = v.x * tv; tr[w0 + 5][cl] = v.y * tv;
    tr[w0 + 6][cl] = v.z * tv; tr[w0 + 7][cl] = v.w * tv;
    __syncthreads();

    const int w  = tid >> 2;           // 0..63
    const int c8 = (tid & 3) << 3;     // 0,8,16,24
    unsigned short o[8] __attribute__((aligned(16)));
    #pragma unroll
    for (int j = 0; j < 8; ++j) o[j] = f2bf(tr[w][c8 + j]);
    size_t dst = ((size_t)((b * 66 + h + 1) * 66) + (w + 1)) * 512 + cic * 32 + c8;
    *(uint4*)&xbp[dst] = *(const uint4*)o;
}

// ---------------- demod coefficient g[b][co] ----------------
__global__ __launch_bounds__(256) void gcoef(
    const float* __restrict__ wsqn, const float* __restrict__ tbuf,
    float* __restrict__ gbuf)
{
    const int b    = blockIdx.y;
    const int co   = blockIdx.x * 4 + (threadIdx.x >> 6);
    const int lane = threadIdx.x & 63;
    float sum = 0.f;
    for (int ci = lane; ci < 512; ci += 64) {
        float tv = tbuf[b * 512 + ci];
        sum = fmaf(tv * tv, wsqn[co * 512 + ci], sum);
    }
    #pragma unroll
    for (int off = 32; off > 0; off >>= 1) sum += __shfl_down(sum, off);
    if (lane == 0)
        gbuf[b * 512 + co] = SCALEV * SCALEV / sqrtf(fmaf(SCALEV * SCALEV, sum, EPSV));
}

// ---------------- main: implicit-GEMM conv, 256co x 128px tile ----------------
// grid (32 px-blocks [16h x 2w], 2 co-blocks, 8 b), 256 threads (4 waves 2x2).
// Per-wave output 128co x 64px (8x4 fragments of 16x16). K-chunk = 64 ci
// (two 32-ci LDS halves), 9 kernel positions reuse the B-tile; A restaged
// per position (single buffer, __syncthreads pairs — proven structure).
// LDS rows (64B = 4x16B chunks) XOR-swizzled: LDS(row,c) = data(row, c^((row>>1)&3)),
// written via inverse-swizzled global source (global_load_lds dest linear),
// read with the same XOR -> conflict-free (verified: SQ_LDS_BANK_CONFLICT==0).
__global__ __launch_bounds__(256, 2) void conv_mfma(
    const unsigned short* __restrict__ xbp, const unsigned short* __restrict__ Aw,
    const float* __restrict__ gbuf, const float* __restrict__ bias,
    const float* __restrict__ noise, const float* __restrict__ nstr,
    float* __restrict__ out)
{
    __shared__ __align__(16) short sA[2][8192];   // hf x 256co x 32ci
    __shared__ __align__(16) short sB[2][6656];   // hf x 208px(6r x 34c) x 32ci

    const int tid  = threadIdx.x;
    const int lane = tid & 63;
    const int wv   = tid >> 6;
    const int b    = blockIdx.z;
    const int co0  = blockIdx.y << 8;
    const int h0   = (blockIdx.x >> 1) << 2;   // output row start (== padded row start)
    const int w0   = (blockIdx.x & 1) << 5;

    const int n0  = lane & 15;
    const int kq  = lane >> 4;
    const int wco = (wv >> 1) << 7;    // 0 or 128
    const int wpx = (wv & 1) << 6;     // 0 or 64

    int pb[4], aoff[8];
    #pragma unroll
    for (int fj = 0; fj < 4; ++fj) {
        int p = wpx + fj * 16 + n0;
        pb[fj] = (p >> 5) * 34 + (p & 31);     // base px index in 6x34 layout
    }
    #pragma unroll
    for (int fi = 0; fi < 8; ++fi) {
        int row = wco + fi * 16 + n0;
        aoff[fi] = row * 32 + (((kq ^ (n0 >> 1)) & 3) << 3);  // swizzled read
    }

    // staging: lane -> row sl_px, source 16B chunk inverse-swizzled so the
    // linear LDS write (dest + lane*16B) lands the swizzled layout.
    const int sl_px = lane >> 2;
    const int sw_ci = (((lane & 3) ^ (sl_px >> 1)) & 3) << 3;

    floatx4 zz = {0.f, 0.f, 0.f, 0.f};
    floatx4 acc[8][4];
    #pragma unroll
    for (int i = 0; i < 8; ++i)
        #pragma unroll
        for (int j = 0; j < 4; ++j) acc[i][j] = zz;

    const unsigned short* xb = xbp + (size_t)b * 4356 * 512;

    for (int ci0 = 0; ci0 < 512; ci0 += 64) {
        __syncthreads();
        // stage B tile: 6 rows x 34 cols x 64 ci (two halves)
        #pragma unroll
        for (int hf = 0; hf < 2; ++hf) {
            const unsigned short* src = xb + ci0 + hf * 32 + sw_ci;
            for (int j = wv; j < 13; j += 4) {
                int px = j * 16 + sl_px;
                if (px > 203) px = 203;
                int row = px / 34;
                int col = px - row * 34;
                gload_lds16(src + (((size_t)(h0 + row) * 66 + w0 + col) << 9),
                            &sB[hf][j * 512]);
            }
        }
        #pragma unroll 1
        for (int pos = 0; pos < 9; ++pos) {
            const int kh = pos / 3;
            const int kw = pos - kh * 3;
            if (pos) __syncthreads();
            // stage A tile for this position: 256co x 64ci
            #pragma unroll
            for (int hf = 0; hf < 2; ++hf) {
                for (int j = wv; j < 16; j += 4) {
                    int co = j * 16 + sl_px;
                    gload_lds16(Aw + (size_t)((co0 + co) * 9 + pos) * 512
                                   + ci0 + hf * 32 + sw_ci,
                                &sA[hf][j * 512]);
                }
            }
            __syncthreads();
            const int dpos = kh * 34 + kw;
            #pragma unroll
            for (int hf = 0; hf < 2; ++hf) {
                short8 af[8], bfr[4];
                #pragma unroll
                for (int fi = 0; fi < 8; ++fi)
                    af[fi] = *(const short8*)&sA[hf][aoff[fi]];
                #pragma unroll
                for (int fj = 0; fj < 4; ++fj) {
                    int pr = pb[fj] + dpos;
                    bfr[fj] = *(const short8*)
                        &sB[hf][pr * 32 + (((kq ^ (pr >> 1)) & 3) << 3)];
                }
                #pragma unroll
                for (int fi = 0; fi < 8; ++fi)
                    #pragma unroll
                    for (int fj = 0; fj < 4; ++fj)
                        acc[fi][fj] = __builtin_amdgcn_mfma_f32_16x16x32_bf16(
                            af[fi], bfr[fj], acc[fi][fj], 0, 0, 0);
            }
        }
    }

    // epilogue: out = g*acc + bias + noise*ns
    const float ns = nstr[0];
    float nz[4];
    int ph[4], pw[4];
    #pragma unroll
    for (int fj = 0; fj < 4; ++fj) {
        int p = wpx + fj * 16 + n0;
        ph[fj] = h0 + (p >> 5);
        pw[fj] = w0 + (p & 31);
        nz[fj] = noise[(b << 12) + (ph[fj] << 6) + pw[fj]] * ns;
    }
    #pragma unroll
    for (int fi = 0; fi < 8; ++fi) {
        #pragma unroll
        for (int i = 0; i < 4; ++i) {
            int co = co0 + wco + fi * 16 + kq * 4 + i;
            float gg = gbuf[(b << 9) + co];
            float bb = bias[co];
            #pragma unroll
            for (int fj = 0; fj < 4; ++fj) {
                out[(((size_t)((b << 9) + co)) << 12) + (ph[fj] << 6) + pw[fj]] =
                    fmaf(gg, acc[fi][fj][i], bb + nz[fj]);
            }
        }
    }
}

extern "C" void kernel_launch(void* const* d_in, const int* in_sizes, int n_in,
                              void* d_out, int out_size, void* d_ws, size_t ws_size,
                              hipStream_t stream)
{
    const float* x      = (const float*)d_in[0];
    const float* style  = (const float*)d_in[1];
    const float* noise  = (const float*)d_in[2];
    const float* weight = (const float*)d_in[3];
    const float* bias   = (const float*)d_in[4];
    const float* nstr   = (const float*)d_in[5];
    float* out = (float*)d_out;
    char* ws = (char*)d_ws;

    // workspace layout (bytes)
    float*          tbuf = (float*)(ws);                    // 16384
    float*          gbuf = (float*)(ws + 16384);            // 16384
    float*          wsqn = (float*)(ws + 32768);            // 1048576
    unsigned short* Aw   = (unsigned short*)(ws + 1081344); // 4718592
    unsigned short* xbp  = (unsigned short*)(ws + 5799936); // 35684352 -> total ~41.5 MB

    hipLaunchKernelGGL(zero_border, dim3(520), dim3(256), 0, stream, (uint4*)xbp);
    hipLaunchKernelGGL(prep_style, dim3(8), dim3(512), 0, stream, style, tbuf);
    hipLaunchKernelGGL(prep_w, dim3(512), dim3(256), 0, stream, weight, wsqn, Aw);
    hipLaunchKernelGGL(prep_x, dim3(16, 64, 8), dim3(256), 0, stream, x, tbuf, xbp);
    hipLaunchKernelGGL(gcoef, dim3(128, 8), dim3(256), 0, stream, wsqn, tbuf, gbuf);
    hipLaunchKernelGGL(conv_mfma, dim3(32, 2, 8), dim3(256), 0, stream,
                       xbp, Aw, gbuf, bias, noise, nstr, out);
}